// Round 6
// baseline (220.437 us; speedup 1.0000x reference)
//
#include <hip/hip_runtime.h>

typedef __bf16 bf16;
typedef __bf16 bf16x8 __attribute__((ext_vector_type(8)));
typedef __bf16 bf16x4 __attribute__((ext_vector_type(4)));
typedef float  f32x4  __attribute__((ext_vector_type(4)));

#define NND   2048      // nodes
#define NBB   8         // batch
#define NPADC 576       // padded panel rows (>= 528, mult of 64)
#define KEXP  3328      // expanded K: 208 ki-chunks * 16 d
#define MTOT  16384     // B*N

__device__ __forceinline__ float sigf(float v) { return 1.f / (1.f + __expf(-v)); }

__device__ __forceinline__ void gl_lds16(const bf16* g, bf16* l) {
  __builtin_amdgcn_global_load_lds(
      (const __attribute__((address_space(1))) void*)g,
      (__attribute__((address_space(3))) void*)l, 16, 0, 0);
}

// ---------------------------------------------------------------
// misc_kernel: grid-fused prep_w (156 blocks) + adj (256) + pack (256)
// ---------------------------------------------------------------
#define PREP_BLKS 156
#define ADJ_BLKS  256
#define PACK_BLKS 256

__global__ __launch_bounds__(256)
void misc_kernel(const float* __restrict__ E, const float* __restrict__ x,
                 const float* __restrict__ state,
                 const float* __restrict__ WpG, const float* __restrict__ BpG,
                 const float* __restrict__ WpU, const float* __restrict__ BpU,
                 bf16* __restrict__ Sbf, bf16* __restrict__ XT,
                 bf16* __restrict__ candT, bf16* __restrict__ BTg,
                 bf16* __restrict__ BTu) {
  __shared__ float tile[66][65];
  int bid = blockIdx.x;
  int t = threadIdx.x;

  if (bid < PREP_BLKS) {
    // ---- prep_w ----
    int which = bid / 52;
    int k0 = (bid % 52) * 64;
    const float* Wp; const float* Bp; bf16* BT; int ncols, o0;
    if (which < 2) { Wp = WpG; Bp = BpG; BT = BTg; ncols = 128; o0 = which * 64; }
    else           { Wp = WpU; Bp = BpU; BT = BTu; ncols = 64;  o0 = 0; }
    for (int idx = t; idx < 4096; idx += 256) {
      int kr = idx >> 6, oc = idx & 63;
      int kp = k0 + kr;
      int ki = kp >> 4, d = kp & 15;
      float v;
      if (ki < 198) {
        int kc3 = ki / 66;
        int i = ki - kc3 * 66;
        v = Wp[(size_t)((d * 3 + kc3) * 66 + i) * ncols + o0 + oc];
      } else if (ki == 198) {
        v = Bp[d * ncols + o0 + oc];
      } else {
        v = 0.f;
      }
      tile[kr][oc] = v;
    }
    __syncthreads();
    for (int idx = t; idx < 4096; idx += 256) {
      int orow = idx >> 6, kc = idx & 63;
      BT[(size_t)(o0 + orow) * KEXP + k0 + kc] = (bf16)tile[kc][orow];
    }
  } else if (bid < PREP_BLKS + ADJ_BLKS) {
    // ---- adj: S = softmax(relu(E E^T)), 8 rows/block, E from L2 ----
    int r0 = (bid - PREP_BLKS) * 8;
    int lane = t & 63, w = t >> 6;
    float* red = &tile[0][0];
    float er[8][16];
#pragma unroll
    for (int r = 0; r < 8; ++r) {
      const f32x4* ep = (const f32x4*)(E + (size_t)(r0 + r) * 16);
#pragma unroll
      for (int qi = 0; qi < 4; ++qi) {
        f32x4 q = ep[qi];
#pragma unroll
        for (int j = 0; j < 4; ++j) er[r][qi * 4 + j] = q[j];
      }
    }
    float v[8][8];
    float mx[8];
#pragma unroll
    for (int r = 0; r < 8; ++r) mx[r] = 0.f;
#pragma unroll
    for (int j = 0; j < 8; ++j) {
      int c = t + j * 256;
      const f32x4* cp = (const f32x4*)(E + (size_t)c * 16);
      float ec[16];
#pragma unroll
      for (int qi = 0; qi < 4; ++qi) {
        f32x4 q = cp[qi];
#pragma unroll
        for (int jj = 0; jj < 4; ++jj) ec[qi * 4 + jj] = q[jj];
      }
#pragma unroll
      for (int r = 0; r < 8; ++r) {
        float s = 0.f;
#pragma unroll
        for (int d = 0; d < 16; ++d) s += er[r][d] * ec[d];
        s = fmaxf(s, 0.f);
        v[r][j] = s;
        mx[r] = fmaxf(mx[r], s);
      }
    }
#pragma unroll
    for (int o = 32; o > 0; o >>= 1)
#pragma unroll
      for (int r = 0; r < 8; ++r) mx[r] = fmaxf(mx[r], __shfl_xor(mx[r], o, 64));
    if (lane == 0)
#pragma unroll
      for (int r = 0; r < 8; ++r) red[w * 8 + r] = mx[r];
    __syncthreads();
#pragma unroll
    for (int r = 0; r < 8; ++r)
      mx[r] = fmaxf(fmaxf(red[r], red[8 + r]), fmaxf(red[16 + r], red[24 + r]));
    float sm[8];
#pragma unroll
    for (int r = 0; r < 8; ++r) sm[r] = 0.f;
#pragma unroll
    for (int j = 0; j < 8; ++j)
#pragma unroll
      for (int r = 0; r < 8; ++r) { v[r][j] = __expf(v[r][j] - mx[r]); sm[r] += v[r][j]; }
#pragma unroll
    for (int o = 32; o > 0; o >>= 1)
#pragma unroll
      for (int r = 0; r < 8; ++r) sm[r] += __shfl_xor(sm[r], o, 64);
    __syncthreads();
    if (lane == 0)
#pragma unroll
      for (int r = 0; r < 8; ++r) red[32 + w * 8 + r] = sm[r];
    __syncthreads();
#pragma unroll
    for (int r = 0; r < 8; ++r) {
      float inv = 1.f / (red[32 + r] + red[40 + r] + red[48 + r] + red[56 + r]);
#pragma unroll
      for (int j = 0; j < 8; ++j)
        Sbf[(size_t)(r0 + r) * NND + t + j * 256] = (bf16)(v[r][j] * inv);
    }
  } else {
    // ---- pack: XT[(b*66+c)][n] = concat(x,state); x-rows also -> candT ----
    int pb = bid - PREP_BLKS - ADJ_BLKS;
    int b  = pb >> 5;
    int n0 = (pb & 31) * 64;
    for (int idx = t; idx < 66 * 64; idx += 256) {
      int nn = idx / 66;
      int c  = idx - nn * 66;
      int bn = (b << 11) + n0 + nn;
      float v = (c < 2) ? x[bn * 2 + c] : state[(bn << 6) + c - 2];
      tile[c][nn] = v;
    }
    __syncthreads();
    for (int idx = t; idx < 66 * 64; idx += 256) {
      int c = idx >> 6;
      int nn = idx & 63;
      bf16 v = (bf16)tile[c][nn];
      size_t off = (size_t)(b * 66 + c) * NND + n0 + nn;
      XT[off] = v;
      if (c < 2) candT[off] = v;
    }
  }
}

// ---------------------------------------------------------------
// graph GEMM: CT[c][n] = sum_k S[n][k] * BT[c][k], bf16 out, z=1.
// 128(n) x 64(c) tile, BK=64, swizzled LDS, gl_lds staging, dbuf.
// grid = (16, 9), 256 thr
// ---------------------------------------------------------------
__global__ __launch_bounds__(256)
void gemm_kernel(const bf16* __restrict__ A, const bf16* __restrict__ BT,
                 bf16* __restrict__ CT) {
  __shared__ bf16 As[2][128 * 64];
  __shared__ bf16 Bs[2][64 * 64];
  int t = threadIdx.x;
  int m0 = blockIdx.x * 128;
  int c0 = blockIdx.y * 64;
  int lane = t & 63, w = t >> 6;
  int wr = w >> 1, wc = w & 1;
  int row16 = lane & 15;
  int kq = (lane >> 4) << 3;

  f32x4 acc[4][2] = {};

  auto stage = [&](int k0, int bb) {
#pragma unroll
    for (int i = 0; i < 4; ++i) {
      int s = i * 256 + t;
      int row = s >> 3;
      int g = ((s & 7) ^ (row & 7)) << 3;
      gl_lds16(A + (size_t)(m0 + row) * NND + k0 + g, &As[bb][s * 8]);
    }
#pragma unroll
    for (int i = 0; i < 2; ++i) {
      int s = i * 256 + t;
      int row = s >> 3;
      int g = ((s & 7) ^ (row & 7)) << 3;
      gl_lds16(BT + (size_t)(c0 + row) * NND + k0 + g, &Bs[bb][s * 8]);
    }
  };

  stage(0, 0);
  __syncthreads();

  int buf = 0;
  for (int s = 0; s < 32; ++s) {
    if (s < 31) stage((s + 1) * 64, buf ^ 1);
#pragma unroll
    for (int kk2 = 0; kk2 < 64; kk2 += 32) {
      int kcg = (kk2 + kq) >> 3;
      bf16x8 a[4], bb2[2];
#pragma unroll
      for (int mi = 0; mi < 4; ++mi) {
        int row = wr * 64 + mi * 16 + row16;
        a[mi] = *(const bf16x8*)&As[buf][row * 64 + ((kcg ^ (row & 7)) << 3)];
      }
#pragma unroll
      for (int ni = 0; ni < 2; ++ni) {
        int row = wc * 32 + ni * 16 + row16;
        bb2[ni] = *(const bf16x8*)&Bs[buf][row * 64 + ((kcg ^ (row & 7)) << 3)];
      }
#pragma unroll
      for (int mi = 0; mi < 4; ++mi)
#pragma unroll
        for (int ni = 0; ni < 2; ++ni)
          acc[mi][ni] = __builtin_amdgcn_mfma_f32_16x16x32_bf16(a[mi], bb2[ni], acc[mi][ni], 0, 0, 0);
    }
    __syncthreads();
    buf ^= 1;
  }

#pragma unroll
  for (int mi = 0; mi < 4; ++mi)
#pragma unroll
    for (int ni = 0; ni < 2; ++ni) {
      int nb = m0 + wr * 64 + mi * 16 + ((lane >> 4) << 2);
      int oc = c0 + wc * 32 + ni * 16 + (lane & 15);
      bf16x4 pb = __builtin_convertvector(acc[mi][ni], bf16x4);
      *(bf16x4*)&CT[(size_t)oc * NND + nb] = pb;
    }
}

// ---------------------------------------------------------------
// wgemm: out[bn][o] = sum_k A'[bn][k] * B'[k][o], z=1, fused epilogue.
// A'[bn][ki*16+d] = xg(bn,ki)*E[n][d] built in LDS (swizzled ds_write).
// 64(bn) x TN(o) tile, BK=64, 52 K-steps. grid = (256), 256 thr.
// GATE: o<64 -> zT=sigmoid; o>=64 -> candT = sig*state.
// !GATE: out = (1-z)*state + z*tanh(acc)
// ---------------------------------------------------------------
template<int TN, int GATE>
__global__ __launch_bounds__(256)
void wgemm_kernel(const bf16* __restrict__ XTsrc, const bf16* __restrict__ Y1src,
                  const bf16* __restrict__ Y2src, const float* __restrict__ E,
                  const bf16* __restrict__ BT, const float* __restrict__ state,
                  float* __restrict__ zT, bf16* __restrict__ candT,
                  float* __restrict__ out) {
  constexpr int NI  = TN / 32;   // B frags per wave
  constexpr int NBI = TN / 32;   // B gl_lds issues
  __shared__ bf16 As[2][64 * 64];
  __shared__ bf16 Bs[2][TN * 64];
  int t = threadIdx.x;
  int m0 = blockIdx.x * 64;
  int lane = t & 63, w = t >> 6;
  int wr = w >> 1, wc = w & 1;
  int row16 = lane & 15, kq = (lane >> 4) << 3;
  int r = t & 63, kh = t >> 6;           // expansion: row r, k-chunk kh (0..3)
  int bn = m0 + r, bidx = bn >> 11, n = bn & 2047;

  float e[16];
  {
    const f32x4* ep = (const f32x4*)(E + (size_t)n * 16);
#pragma unroll
    for (int qi = 0; qi < 4; ++qi) {
      f32x4 q = ep[qi];
#pragma unroll
      for (int j = 0; j < 4; ++j) e[qi * 4 + j] = q[j];
    }
  }

  f32x4 acc[2][NI] = {};

  auto loadx = [&](int ki) -> float {
    if (ki < 66)  return (float)XTsrc[(size_t)(bidx * 66 + ki) * NND + n];
    if (ki < 132) return (float)Y1src[(size_t)(bidx * 66 + ki - 66) * NND + n];
    if (ki < 198) {
      size_t off = (size_t)(bidx * 66 + ki - 132) * NND + n;
      return 2.f * (float)Y2src[off] - (float)XTsrc[off];
    }
    return (ki == 198) ? 1.f : 0.f;
  };
  auto expand = [&](int bb, float xv) {
#pragma unroll
    for (int p = 0; p < 2; ++p) {
      bf16x8 pk;
#pragma unroll
      for (int j = 0; j < 8; ++j) pk[j] = (bf16)(xv * e[p * 8 + j]);
      int gidx = ((kh * 2 + p) ^ (r & 7)) << 3;
      *(bf16x8*)&As[bb][r * 64 + gidx] = pk;
    }
  };
  auto stageB = [&](int k0, int bb) {
#pragma unroll
    for (int i = 0; i < NBI; ++i) {
      int s = i * 256 + t;
      int row = s >> 3;
      int g = ((s & 7) ^ (row & 7)) << 3;
      gl_lds16(BT + (size_t)row * KEXP + k0 + g, &Bs[bb][s * 8]);
    }
  };
  auto mstep = [&](int bb) {
#pragma unroll
    for (int kk2 = 0; kk2 < 64; kk2 += 32) {
      int kcg = (kk2 + kq) >> 3;
      bf16x8 af[2], bfg[NI];
#pragma unroll
      for (int mi = 0; mi < 2; ++mi) {
        int row = wr * 32 + mi * 16 + row16;
        af[mi] = *(const bf16x8*)&As[bb][row * 64 + ((kcg ^ (row & 7)) << 3)];
      }
#pragma unroll
      for (int ni = 0; ni < NI; ++ni) {
        int row = wc * (TN / 2) + ni * 16 + row16;
        bfg[ni] = *(const bf16x8*)&Bs[bb][row * 64 + ((kcg ^ (row & 7)) << 3)];
      }
#pragma unroll
      for (int mi = 0; mi < 2; ++mi)
#pragma unroll
        for (int ni = 0; ni < NI; ++ni)
          acc[mi][ni] = __builtin_amdgcn_mfma_f32_16x16x32_bf16(af[mi], bfg[ni], acc[mi][ni], 0, 0, 0);
    }
  };

  // prologue
  {
    float xv0 = loadx(kh);
    stageB(0, 0);
    expand(0, xv0);
  }
  __syncthreads();

  int buf = 0;
  for (int s = 0; s < 52; ++s) {
    float xvn = 0.f;
    if (s < 51) {
      stageB((s + 1) * 64, buf ^ 1);
      xvn = loadx((s + 1) * 4 + kh);
    }
    mstep(buf);
    __syncthreads();                 // MFMA reads of buf done; gl_lds(buf^1) drained
    if (s < 51) {
      expand(buf ^ 1, xvn);
      __syncthreads();               // As[buf^1] visible
    }
    buf ^= 1;
  }

  // fused epilogue: stage state tile (64x64 f32) into As space
  __syncthreads();
  float* stf = (float*)&As[0][0];    // 16 KB = As total
#pragma unroll
  for (int i = 0; i < 16; ++i) {
    int idx = i * 256 + t;
    int rr = idx >> 6, cc = idx & 63;
    stf[rr * 64 + cc] = state[(size_t)(m0 + rr) * 64 + cc];
  }
  __syncthreads();

#pragma unroll
  for (int mi = 0; mi < 2; ++mi)
#pragma unroll
    for (int ni = 0; ni < NI; ++ni) {
      int nb = m0 + wr * 32 + mi * 16 + ((lane >> 4) << 2);
      int oc = wc * (TN / 2) + ni * 16 + (lane & 15);
      int rb = nb - m0;
      f32x4 a = acc[mi][ni];
      if (GATE) {
        if (oc < 64) {
          f32x4 zv = { sigf(a[0]), sigf(a[1]), sigf(a[2]), sigf(a[3]) };
          *(f32x4*)&zT[(size_t)oc * MTOT + nb] = zv;
        } else {
          int h = oc - 64;
          bf16x4 cv;
#pragma unroll
          for (int j = 0; j < 4; ++j)
            cv[j] = (bf16)(sigf(a[j]) * stf[(rb + j) * 64 + h]);
          int b2 = nb >> 11, n2 = nb & 2047;
          *(bf16x4*)&candT[(size_t)(b2 * 66 + 2 + h) * NND + n2] = cv;
        }
      } else {
        f32x4 zv = *(const f32x4*)&zT[(size_t)oc * MTOT + nb];
#pragma unroll
        for (int j = 0; j < 4; ++j) {
          float hc = tanhf(a[j]);
          float s0 = stf[(rb + j) * 64 + oc];
          out[(size_t)(nb + j) * 64 + oc] = (1.f - zv[j]) * s0 + zv[j] * hc;
        }
      }
    }
}

// ---------------------------------------------------------------
extern "C" void kernel_launch(void* const* d_in, const int* in_sizes, int n_in,
                              void* d_out, int out_size, void* d_ws, size_t ws_size,
                              hipStream_t stream) {
  const float* x     = (const float*)d_in[0];
  const float* state = (const float*)d_in[1];
  const float* E     = (const float*)d_in[2];
  const float* WpG   = (const float*)d_in[3];
  const float* BpG   = (const float*)d_in[4];
  const float* WpU   = (const float*)d_in[5];
  const float* BpU   = (const float*)d_in[6];
  float* out = (float*)d_out;

  char* p = (char*)d_ws;
  bf16*  Sbf   = (bf16*)p;  p += (size_t)NND * NND * 2;       // 8 MB
  bf16*  XT    = (bf16*)p;  p += (size_t)NPADC * NND * 2;     // 2.25 MB
  bf16*  candT = (bf16*)p;  p += (size_t)NPADC * NND * 2;     // 2.25 MB
  bf16*  Y1bf  = (bf16*)p;  p += (size_t)NPADC * NND * 2;     // 2.25 MB (also Z1)
  bf16*  Y2bf  = (bf16*)p;  p += (size_t)NPADC * NND * 2;     // 2.25 MB (also Z2)
  float* zT    = (float*)p; p += (size_t)64 * MTOT * 4;       // 4 MB
  bf16*  BTg   = (bf16*)p;  p += (size_t)128 * KEXP * 2;      // 832 KB
  bf16*  BTu   = (bf16*)p;  p += (size_t)64 * KEXP * 2;       // 416 KB

  dim3 b256(256);
  dim3 gemmGrid(NND / 128, NPADC / 64);

  misc_kernel<<<PREP_BLKS + ADJ_BLKS + PACK_BLKS, b256, 0, stream>>>(
      E, x, state, WpG, BpG, WpU, BpU, Sbf, XT, candT, BTg, BTu);

  gemm_kernel<<<gemmGrid, b256, 0, stream>>>(Sbf, XT, Y1bf);
  gemm_kernel<<<gemmGrid, b256, 0, stream>>>(Sbf, Y1bf, Y2bf);
  wgemm_kernel<128, 1><<<MTOT / 64, b256, 0, stream>>>(XT, Y1bf, Y2bf, E, BTg,
                                                       state, zT, candT, nullptr);
  gemm_kernel<<<gemmGrid, b256, 0, stream>>>(Sbf, candT, Y1bf);
  gemm_kernel<<<gemmGrid, b256, 0, stream>>>(Sbf, Y1bf, Y2bf);
  wgemm_kernel<64, 0><<<MTOT / 64, b256, 0, stream>>>(candT, Y1bf, Y2bf, E, BTu,
                                                      state, zT, nullptr, out);
}

// Round 7
// 182.333 us; speedup vs baseline: 1.2090x; 1.2090x over previous
//
#include <hip/hip_runtime.h>

typedef __bf16 bf16;
typedef __bf16 bf16x8 __attribute__((ext_vector_type(8)));
typedef __bf16 bf16x4 __attribute__((ext_vector_type(4)));
typedef float  f32x4  __attribute__((ext_vector_type(4)));

#define NND   2048      // nodes
#define NBB   8         // batch
#define NPADC 576       // padded panel rows (>= 528, mult of 64)
#define KEXP  3328      // expanded K: 208 ki-chunks * 16 d
#define MTOT  16384     // B*N

__device__ __forceinline__ float sigf(float v) { return 1.f / (1.f + __expf(-v)); }

__device__ __forceinline__ void gl_lds16(const bf16* g, bf16* l) {
  __builtin_amdgcn_global_load_lds(
      (const __attribute__((address_space(1))) void*)g,
      (__attribute__((address_space(3))) void*)l, 16, 0, 0);
}

// ---------------------------------------------------------------
// misc_kernel: grid-fused prep_w (156 blocks) + adj (256) + pack (256)
// ---------------------------------------------------------------
#define PREP_BLKS 156
#define ADJ_BLKS  256
#define PACK_BLKS 256

__global__ __launch_bounds__(256)
void misc_kernel(const float* __restrict__ E, const float* __restrict__ x,
                 const float* __restrict__ state,
                 const float* __restrict__ WpG, const float* __restrict__ BpG,
                 const float* __restrict__ WpU, const float* __restrict__ BpU,
                 bf16* __restrict__ Sbf, bf16* __restrict__ XT,
                 bf16* __restrict__ candT, bf16* __restrict__ BTg,
                 bf16* __restrict__ BTu) {
  __shared__ float tile[66][65];
  int bid = blockIdx.x;
  int t = threadIdx.x;

  if (bid < PREP_BLKS) {
    int which = bid / 52;
    int k0 = (bid % 52) * 64;
    const float* Wp; const float* Bp; bf16* BT; int ncols, o0;
    if (which < 2) { Wp = WpG; Bp = BpG; BT = BTg; ncols = 128; o0 = which * 64; }
    else           { Wp = WpU; Bp = BpU; BT = BTu; ncols = 64;  o0 = 0; }
    for (int idx = t; idx < 4096; idx += 256) {
      int kr = idx >> 6, oc = idx & 63;
      int kp = k0 + kr;
      int ki = kp >> 4, d = kp & 15;
      float v;
      if (ki < 198) {
        int kc3 = ki / 66;
        int i = ki - kc3 * 66;
        v = Wp[(size_t)((d * 3 + kc3) * 66 + i) * ncols + o0 + oc];
      } else if (ki == 198) {
        v = Bp[d * ncols + o0 + oc];
      } else {
        v = 0.f;
      }
      tile[kr][oc] = v;
    }
    __syncthreads();
    for (int idx = t; idx < 4096; idx += 256) {
      int orow = idx >> 6, kc = idx & 63;
      BT[(size_t)(o0 + orow) * KEXP + k0 + kc] = (bf16)tile[kc][orow];
    }
  } else if (bid < PREP_BLKS + ADJ_BLKS) {
    // adj: S = softmax(relu(E E^T)), 8 rows/block
    int r0 = (bid - PREP_BLKS) * 8;
    int lane = t & 63, w = t >> 6;
    float* red = &tile[0][0];
    float er[8][16];
#pragma unroll
    for (int r = 0; r < 8; ++r) {
      const f32x4* ep = (const f32x4*)(E + (size_t)(r0 + r) * 16);
#pragma unroll
      for (int qi = 0; qi < 4; ++qi) {
        f32x4 q = ep[qi];
#pragma unroll
        for (int j = 0; j < 4; ++j) er[r][qi * 4 + j] = q[j];
      }
    }
    float v[8][8];
    float mx[8];
#pragma unroll
    for (int r = 0; r < 8; ++r) mx[r] = 0.f;
#pragma unroll
    for (int j = 0; j < 8; ++j) {
      int c = t + j * 256;
      const f32x4* cp = (const f32x4*)(E + (size_t)c * 16);
      float ec[16];
#pragma unroll
      for (int qi = 0; qi < 4; ++qi) {
        f32x4 q = cp[qi];
#pragma unroll
        for (int jj = 0; jj < 4; ++jj) ec[qi * 4 + jj] = q[jj];
      }
#pragma unroll
      for (int r = 0; r < 8; ++r) {
        float s = 0.f;
#pragma unroll
        for (int d = 0; d < 16; ++d) s += er[r][d] * ec[d];
        s = fmaxf(s, 0.f);
        v[r][j] = s;
        mx[r] = fmaxf(mx[r], s);
      }
    }
#pragma unroll
    for (int o = 32; o > 0; o >>= 1)
#pragma unroll
      for (int r = 0; r < 8; ++r) mx[r] = fmaxf(mx[r], __shfl_xor(mx[r], o, 64));
    if (lane == 0)
#pragma unroll
      for (int r = 0; r < 8; ++r) red[w * 8 + r] = mx[r];
    __syncthreads();
#pragma unroll
    for (int r = 0; r < 8; ++r)
      mx[r] = fmaxf(fmaxf(red[r], red[8 + r]), fmaxf(red[16 + r], red[24 + r]));
    float sm[8];
#pragma unroll
    for (int r = 0; r < 8; ++r) sm[r] = 0.f;
#pragma unroll
    for (int j = 0; j < 8; ++j)
#pragma unroll
      for (int r = 0; r < 8; ++r) { v[r][j] = __expf(v[r][j] - mx[r]); sm[r] += v[r][j]; }
#pragma unroll
    for (int o = 32; o > 0; o >>= 1)
#pragma unroll
      for (int r = 0; r < 8; ++r) sm[r] += __shfl_xor(sm[r], o, 64);
    __syncthreads();
    if (lane == 0)
#pragma unroll
      for (int r = 0; r < 8; ++r) red[32 + w * 8 + r] = sm[r];
    __syncthreads();
#pragma unroll
    for (int r = 0; r < 8; ++r) {
      float inv = 1.f / (red[32 + r] + red[40 + r] + red[48 + r] + red[56 + r]);
#pragma unroll
      for (int j = 0; j < 8; ++j)
        Sbf[(size_t)(r0 + r) * NND + t + j * 256] = (bf16)(v[r][j] * inv);
    }
  } else {
    // pack: XT[(b*66+c)][n] = concat(x,state); x-rows also -> candT
    int pb = bid - PREP_BLKS - ADJ_BLKS;
    int b  = pb >> 5;
    int n0 = (pb & 31) * 64;
    for (int idx = t; idx < 66 * 64; idx += 256) {
      int nn = idx / 66;
      int c  = idx - nn * 66;
      int bn = (b << 11) + n0 + nn;
      float v = (c < 2) ? x[bn * 2 + c] : state[(bn << 6) + c - 2];
      tile[c][nn] = v;
    }
    __syncthreads();
    for (int idx = t; idx < 66 * 64; idx += 256) {
      int c = idx >> 6;
      int nn = idx & 63;
      bf16 v = (bf16)tile[c][nn];
      size_t off = (size_t)(b * 66 + c) * NND + n0 + nn;
      XT[off] = v;
      if (c < 2) candT[off] = v;
    }
  }
}

// ---------------------------------------------------------------
// graph GEMM partials: P[z][c][n] = sum_{k in z-quarter} S[n][k]*BT[c][k]
// 64x64 tile, BK=64, gl_lds + XOR swizzle, dbuf. grid (32, 9, 4), 256 thr.
// ---------------------------------------------------------------
__global__ __launch_bounds__(256)
void gemm_kernel(const bf16* __restrict__ A, const bf16* __restrict__ BT,
                 float* __restrict__ P) {
  __shared__ bf16 As[2][64 * 64];
  __shared__ bf16 Bs[2][64 * 64];
  int t = threadIdx.x;
  int m0 = blockIdx.x * 64;
  int c0 = blockIdx.y * 64;
  int z  = blockIdx.z;
  int lane = t & 63, w = t >> 6;
  int wr = w >> 1, wc = w & 1;
  int row16 = lane & 15;
  int kq = (lane >> 4) << 3;
  int kbase = z * 512;

  f32x4 acc[2][2] = {};

  auto stage = [&](int k0, int bb) {
#pragma unroll
    for (int i = 0; i < 2; ++i) {
      int s = i * 256 + t;
      int row = s >> 3;
      int g = ((s & 7) ^ (row & 7)) << 3;
      gl_lds16(A  + (size_t)(m0 + row) * NND + k0 + g, &As[bb][s * 8]);
      gl_lds16(BT + (size_t)(c0 + row) * NND + k0 + g, &Bs[bb][s * 8]);
    }
  };

  stage(kbase, 0);
  __syncthreads();

  int buf = 0;
  for (int s = 0; s < 8; ++s) {
    if (s < 7) stage(kbase + (s + 1) * 64, buf ^ 1);
#pragma unroll
    for (int kk2 = 0; kk2 < 64; kk2 += 32) {
      int kcg = (kk2 + kq) >> 3;
      bf16x8 af[2], bfg[2];
#pragma unroll
      for (int mi = 0; mi < 2; ++mi) {
        int row = wr * 32 + mi * 16 + row16;
        af[mi] = *(const bf16x8*)&As[buf][row * 64 + ((kcg ^ (row & 7)) << 3)];
      }
#pragma unroll
      for (int ni = 0; ni < 2; ++ni) {
        int row = wc * 32 + ni * 16 + row16;
        bfg[ni] = *(const bf16x8*)&Bs[buf][row * 64 + ((kcg ^ (row & 7)) << 3)];
      }
#pragma unroll
      for (int mi = 0; mi < 2; ++mi)
#pragma unroll
        for (int ni = 0; ni < 2; ++ni)
          acc[mi][ni] = __builtin_amdgcn_mfma_f32_16x16x32_bf16(af[mi], bfg[ni], acc[mi][ni], 0, 0, 0);
    }
    __syncthreads();
    buf ^= 1;
  }

#pragma unroll
  for (int mi = 0; mi < 2; ++mi)
#pragma unroll
    for (int ni = 0; ni < 2; ++ni) {
      int nb = m0 + wr * 32 + mi * 16 + ((lane >> 4) << 2);
      int oc = c0 + wc * 32 + ni * 16 + (lane & 15);
      *(f32x4*)&P[((size_t)z * NPADC + oc) * NND + nb] = acc[mi][ni];
    }
}

// ---------------------------------------------------------------
// reduce 4 partials -> bf16. grid 1152.
// ---------------------------------------------------------------
__global__ __launch_bounds__(256)
void reduce_kernel(const float* __restrict__ P, bf16* __restrict__ Y) {
  size_t i = ((size_t)blockIdx.x * 256 + threadIdx.x) * 4;
  const size_t PL = (size_t)NPADC * NND;
  f32x4 s = *(const f32x4*)&P[i];
  s += *(const f32x4*)&P[PL + i];
  s += *(const f32x4*)&P[2 * PL + i];
  s += *(const f32x4*)&P[3 * PL + i];
  *(bf16x4*)&Y[i] = __builtin_convertvector(s, bf16x4);
}

// ---------------------------------------------------------------
// wgemm partials: P[z][oc0+oc][bn] = sum_{k in z-half} A'[bn][k]*B'[k][oc]
// A'[bn][ki*16+d] = xg(bn,ki)*E[n][d] built in LDS (swizzled ds_write).
// 64x64 tile, BK=64, 26 steps. grid (256, ncols/64, 2), 256 thr.
// ---------------------------------------------------------------
template<int NCOLS>
__global__ __launch_bounds__(256)
void wgemm_kernel(const bf16* __restrict__ XTsrc, const bf16* __restrict__ Y1src,
                  const bf16* __restrict__ Y2src, const float* __restrict__ E,
                  const bf16* __restrict__ BT, float* __restrict__ P) {
  __shared__ bf16 As[2][64 * 64];
  __shared__ bf16 Bs[2][64 * 64];
  int t = threadIdx.x;
  int m0 = blockIdx.x * 64;
  int oc0 = blockIdx.y * 64;
  int z = blockIdx.z;
  const bf16* BTb = BT + (size_t)oc0 * KEXP;
  int lane = t & 63, w = t >> 6;
  int wr = w >> 1, wc = w & 1;
  int row16 = lane & 15, kq = (lane >> 4) << 3;
  int r = t & 63, kh = t >> 6;             // expansion ids
  int bn = m0 + r, bidx = bn >> 11, n = bn & 2047;
  const int kbase = z * (KEXP / 2);        // 1664
  const int kibase = z * (KEXP / 32);      // 104

  float e[16];
  {
    const f32x4* ep = (const f32x4*)(E + (size_t)n * 16);
#pragma unroll
    for (int qi = 0; qi < 4; ++qi) {
      f32x4 q = ep[qi];
#pragma unroll
      for (int j = 0; j < 4; ++j) e[qi * 4 + j] = q[j];
    }
  }

  f32x4 acc[2][2] = {};

  auto loadx = [&](int ki) -> float {
    if (ki < 66)  return (float)XTsrc[(size_t)(bidx * 66 + ki) * NND + n];
    if (ki < 132) return (float)Y1src[(size_t)(bidx * 66 + ki - 66) * NND + n];
    if (ki < 198) {
      size_t off = (size_t)(bidx * 66 + ki - 132) * NND + n;
      return 2.f * (float)Y2src[off] - (float)XTsrc[off];
    }
    return (ki == 198) ? 1.f : 0.f;
  };
  auto expand = [&](int bb, float xv) {
#pragma unroll
    for (int p = 0; p < 2; ++p) {
      bf16x8 pk;
#pragma unroll
      for (int j = 0; j < 8; ++j) pk[j] = (bf16)(xv * e[p * 8 + j]);
      int gidx = ((kh * 2 + p) ^ (r & 7)) << 3;
      *(bf16x8*)&As[bb][r * 64 + gidx] = pk;
    }
  };
  auto stageB = [&](int k0, int bb) {
#pragma unroll
    for (int i = 0; i < 2; ++i) {
      int s = i * 256 + t;
      int row = s >> 3;
      int g = ((s & 7) ^ (row & 7)) << 3;
      gl_lds16(BTb + (size_t)row * KEXP + k0 + g, &Bs[bb][s * 8]);
    }
  };
  auto mstep = [&](int bb) {
#pragma unroll
    for (int kk2 = 0; kk2 < 64; kk2 += 32) {
      int kcg = (kk2 + kq) >> 3;
      bf16x8 af[2], bfg[2];
#pragma unroll
      for (int mi = 0; mi < 2; ++mi) {
        int row = wr * 32 + mi * 16 + row16;
        af[mi] = *(const bf16x8*)&As[bb][row * 64 + ((kcg ^ (row & 7)) << 3)];
      }
#pragma unroll
      for (int ni = 0; ni < 2; ++ni) {
        int row = wc * 32 + ni * 16 + row16;
        bfg[ni] = *(const bf16x8*)&Bs[bb][row * 64 + ((kcg ^ (row & 7)) << 3)];
      }
#pragma unroll
      for (int mi = 0; mi < 2; ++mi)
#pragma unroll
        for (int ni = 0; ni < 2; ++ni)
          acc[mi][ni] = __builtin_amdgcn_mfma_f32_16x16x32_bf16(af[mi], bfg[ni], acc[mi][ni], 0, 0, 0);
    }
  };

  // prologue
  {
    float xv0 = loadx(kibase + kh);
    stageB(kbase, 0);
    expand(0, xv0);
  }
  __syncthreads();

  int buf = 0;
  for (int s = 0; s < 26; ++s) {
    float xvn = 0.f;
    if (s < 25) {
      stageB(kbase + (s + 1) * 64, buf ^ 1);
      xvn = loadx(kibase + (s + 1) * 4 + kh);
    }
    mstep(buf);
    __syncthreads();                 // MFMA reads of buf done; gl_lds(buf^1) drained
    if (s < 25) {
      expand(buf ^ 1, xvn);
      __syncthreads();               // As[buf^1] visible
    }
    buf ^= 1;
  }

#pragma unroll
  for (int mi = 0; mi < 2; ++mi)
#pragma unroll
    for (int ni = 0; ni < 2; ++ni) {
      int nb = m0 + wr * 32 + mi * 16 + ((lane >> 4) << 2);
      int oc = oc0 + wc * 32 + ni * 16 + (lane & 15);
      *(f32x4*)&P[((size_t)z * NCOLS + oc) * MTOT + nb] = acc[mi][ni];
    }
}

// ---------------------------------------------------------------
// gate epilogue (z=2 partials): zT = sig(z-sum); candT = sig(r-sum)*state
// grid = MTOT/64
// ---------------------------------------------------------------
__global__ __launch_bounds__(256)
void gate_epi(const float* __restrict__ P, const float* __restrict__ state,
              float* __restrict__ zT, bf16* __restrict__ candT) {
  __shared__ float st[64][65];
  int bn0 = blockIdx.x * 64;
  int t = threadIdx.x;
#pragma unroll
  for (int i = 0; i < 16; ++i) {
    int e = i * 256 + t;
    int bnr = e >> 6, hc = e & 63;
    st[hc][bnr] = state[(size_t)(bn0 + bnr) * 64 + hc];
  }
  __syncthreads();
#pragma unroll
  for (int i = 0; i < 4; ++i) {
    int pr = i * 256 + t;
    int h = pr >> 4, bl = (pr & 15) * 4;
    int bn = bn0 + bl;
    f32x4 zs = *(const f32x4*)&P[(size_t)h * MTOT + bn];
    zs      += *(const f32x4*)&P[(size_t)(128 + h) * MTOT + bn];
    f32x4 rs = *(const f32x4*)&P[(size_t)(64 + h) * MTOT + bn];
    rs      += *(const f32x4*)&P[(size_t)(192 + h) * MTOT + bn];
    f32x4 zv; bf16x4 cv;
#pragma unroll
    for (int j = 0; j < 4; ++j) {
      zv[j] = sigf(zs[j]);
      cv[j] = (bf16)(sigf(rs[j]) * st[h][bl + j]);
    }
    *(f32x4*)&zT[(size_t)h * MTOT + bn] = zv;
    int b = bn >> 11, n = bn & 2047;
    *(bf16x4*)&candT[(size_t)(b * 66 + 2 + h) * NND + n] = cv;
  }
}

// ---------------------------------------------------------------
// update epilogue (z=2 partials): out = (1-z)*state + z*tanh(sum)
// grid = MTOT/64
// ---------------------------------------------------------------
__global__ __launch_bounds__(256)
void update_epi(const float* __restrict__ P, const float* __restrict__ state,
                const float* __restrict__ zT, float* __restrict__ out) {
  __shared__ float st[64][65];
  int bn0 = blockIdx.x * 64;
  int t = threadIdx.x;
#pragma unroll
  for (int i = 0; i < 16; ++i) {
    int e = i * 256 + t;
    int bnr = e >> 6, oc = e & 63;
    st[oc][bnr] = state[(size_t)(bn0 + bnr) * 64 + oc];
  }
  __syncthreads();
#pragma unroll
  for (int i = 0; i < 4; ++i) {
    int pr = i * 256 + t;
    int o = pr >> 4, bl = (pr & 15) * 4;
    int bn = bn0 + bl;
    f32x4 ps = *(const f32x4*)&P[(size_t)o * MTOT + bn];
    ps      += *(const f32x4*)&P[(size_t)(64 + o) * MTOT + bn];
    f32x4 zv = *(const f32x4*)&zT[(size_t)o * MTOT + bn];
#pragma unroll
    for (int j = 0; j < 4; ++j) {
      float hc = tanhf(ps[j]);
      float s0 = st[o][bl + j];
      st[o][bl + j] = (1.f - zv[j]) * s0 + zv[j] * hc;
    }
  }
  __syncthreads();
#pragma unroll
  for (int i = 0; i < 16; ++i) {
    int e = i * 256 + t;
    int bnr = e >> 6, oc = e & 63;
    out[(size_t)(bn0 + bnr) * 64 + oc] = st[oc][bnr];
  }
}

// ---------------------------------------------------------------
extern "C" void kernel_launch(void* const* d_in, const int* in_sizes, int n_in,
                              void* d_out, int out_size, void* d_ws, size_t ws_size,
                              hipStream_t stream) {
  const float* x     = (const float*)d_in[0];
  const float* state = (const float*)d_in[1];
  const float* E     = (const float*)d_in[2];
  const float* WpG   = (const float*)d_in[3];
  const float* BpG   = (const float*)d_in[4];
  const float* WpU   = (const float*)d_in[5];
  const float* BpU   = (const float*)d_in[6];
  float* out = (float*)d_out;

  char* p = (char*)d_ws;
  bf16*  Sbf   = (bf16*)p;  p += (size_t)NND * NND * 2;       // 8 MB
  bf16*  XT    = (bf16*)p;  p += (size_t)NPADC * NND * 2;     // 2.25 MB
  bf16*  candT = (bf16*)p;  p += (size_t)NPADC * NND * 2;     // 2.25 MB
  bf16*  Y1bf  = (bf16*)p;  p += (size_t)NPADC * NND * 2;     // 2.25 MB (also Z1)
  bf16*  Y2bf  = (bf16*)p;  p += (size_t)NPADC * NND * 2;     // 2.25 MB (also Z2)
  float* zT    = (float*)p; p += (size_t)64 * MTOT * 4;       // 4 MB
  bf16*  BTg   = (bf16*)p;  p += (size_t)128 * KEXP * 2;      // 832 KB
  bf16*  BTu   = (bf16*)p;  p += (size_t)64 * KEXP * 2;       // 416 KB
  float* P     = (float*)p; p += (size_t)4 * NPADC * NND * 4; // 18.9 MB (shared partials)

  dim3 b256(256);
  dim3 gemmGrid(NND / 64, NPADC / 64, 4);
  int redGrid = NPADC * NND / 1024;

  misc_kernel<<<PREP_BLKS + ADJ_BLKS + PACK_BLKS, b256, 0, stream>>>(
      E, x, state, WpG, BpG, WpU, BpU, Sbf, XT, candT, BTg, BTu);

  gemm_kernel<<<gemmGrid, b256, 0, stream>>>(Sbf, XT, P);
  reduce_kernel<<<redGrid, b256, 0, stream>>>(P, Y1bf);
  gemm_kernel<<<gemmGrid, b256, 0, stream>>>(Sbf, Y1bf, P);
  reduce_kernel<<<redGrid, b256, 0, stream>>>(P, Y2bf);
  wgemm_kernel<128><<<dim3(MTOT / 64, 2, 2), b256, 0, stream>>>(XT, Y1bf, Y2bf, E, BTg, P);
  gate_epi<<<MTOT / 64, b256, 0, stream>>>(P, state, zT, candT);

  gemm_kernel<<<gemmGrid, b256, 0, stream>>>(Sbf, candT, P);
  reduce_kernel<<<redGrid, b256, 0, stream>>>(P, Y1bf);
  gemm_kernel<<<gemmGrid, b256, 0, stream>>>(Sbf, Y1bf, P);
  reduce_kernel<<<redGrid, b256, 0, stream>>>(P, Y2bf);
  wgemm_kernel<64><<<dim3(MTOT / 64, 1, 2), b256, 0, stream>>>(candT, Y1bf, Y2bf, E, BTu, P);
  update_epi<<<MTOT / 64, b256, 0, stream>>>(P, state, zT, out);
}